// Round 3
// baseline (482.078 us; speedup 1.0000x reference)
//
#include <hip/hip_runtime.h>

#define NB 8
#define NC 512
#define NQ 64
#define NN 9216
#define FEPS 1e-6f

typedef __attribute__((ext_vector_type(8))) short s16x8;
typedef __attribute__((ext_vector_type(4))) float f32x4;

// workspace layout (floats)
static const size_t OFF_Q    = 0;                                  // Qtb bf16 [B][N][64] swizzled
static const size_t OFF_KT   = OFF_Q + (size_t)NB * NQ * NN;       // Wvb bf16 [512][512] (reuses old Kt region)
static const size_t OFF_KSUM = OFF_KT + (size_t)NB * NQ * NN;      // [B][64]
static const size_t OFF_XSUM = OFF_KSUM + (size_t)NB * NQ;         // [B][512]
static const size_t OFF_M1   = OFF_XSUM + (size_t)NB * NC;         // [B][64][512]
static const size_t OFF_M2   = OFF_M1 + (size_t)NB * NQ * NC;      // m2bT bf16 [B][512][64] swizzled
static const size_t OFF_VSUM = OFF_M2 + (size_t)NB * NQ * NC;      // [B][512]
static const size_t OFF_WB   = OFF_VSUM + (size_t)NB * NC;         // bf16 [128][512]

__device__ __forceinline__ void load_lds16(const void* g, void* l) {
    __builtin_amdgcn_global_load_lds((const __attribute__((address_space(1))) void*)g,
                                     (__attribute__((address_space(3))) void*)l, 16, 0, 0);
}

__device__ __forceinline__ unsigned cvt_pk_bf16(float lo, float hi) {
    unsigned r;
    asm("v_cvt_pk_bf16_f32 %0, %1, %2" : "=v"(r) : "v"(lo), "v"(hi));
    return r;
}

__device__ __forceinline__ unsigned short f2bf(float f) {
    union { float f; unsigned u; } a; a.f = f;
    unsigned r = a.u + 0x7FFFu + ((a.u >> 16) & 1u);
    return (unsigned short)(r >> 16);
}

// -------- one-time weight conversion: Wb[128][512] (wq|wk), Wvb[512][512] --------
__global__ void prep_w_kernel(const float* __restrict__ wq, const float* __restrict__ wk,
                              const float* __restrict__ wv,
                              unsigned short* __restrict__ Wb, unsigned short* __restrict__ Wvb) {
    if (blockIdx.x < 16) {
        const int idx = blockIdx.x * 256 + threadIdx.x;
#pragma unroll
        for (int k = 0; k < 4; ++k) {
            const int f4 = idx + k * 4096;  // 0..16383
            const float* src = (f4 < 8192) ? wq : wk;
            const float4 v = *(const float4*)&src[(size_t)(f4 & 8191) * 4];
            uint2 u;
            u.x = cvt_pk_bf16(v.x, v.y);
            u.y = cvt_pk_bf16(v.z, v.w);
            *(uint2*)&Wb[(size_t)f4 * 4] = u;
        }
    } else {
        const int idx = (blockIdx.x - 16) * 256 + threadIdx.x;
#pragma unroll
        for (int k = 0; k < 4; ++k) {
            const int f4 = idx + k * 16384;  // 0..65535
            const float4 v = *(const float4*)&wv[(size_t)f4 * 4];
            uint2 u;
            u.x = cvt_pk_bf16(v.x, v.y);
            u.y = cvt_pk_bf16(v.z, v.w);
            *(uint2*)&Wvb[(size_t)f4 * 4] = u;
        }
    }
}

// -------- FUSED: Q/K projection (bf16 MFMA) + L2 norm + ksum + mat1 += K·x^T + xsum --------
// grid (144, 8), block 256 (4 waves). Per block: 128 outputs (64 Q + 64 K) x 64 positions,
// then mat1[b][64o][512c] contribution for these 64 positions via 8 c-chunk MFMAs + atomics.
__launch_bounds__(256, 3)
__global__ void qk_mfma_kernel(const float* __restrict__ x,
                               const unsigned short* __restrict__ Wb,
                               const float* __restrict__ bq, const float* __restrict__ bk,
                               unsigned short* __restrict__ Qtb,
                               float* __restrict__ ksum, float* __restrict__ xsum,
                               float* __restrict__ mat1) {
    __shared__ __align__(16) unsigned short WX[12672];
    __shared__ float ssqL[4][64];
    unsigned short* Ws = WX;           // [128][64]  main loop
    unsigned short* Xs = WX + 8192;    // [64][64]   main loop
    const int t = threadIdx.x;
    const int w = t >> 6, lane = t & 63;
    const int g = lane >> 4, i16 = lane & 15;
    const int b = blockIdx.y;
    const int n0 = blockIdx.x * 64;
    const int srow = (w << 3) + (lane >> 3);
    const int sslot = lane & 7;

    f32x4 acc[2][4];
#pragma unroll
    for (int rt = 0; rt < 2; ++rt)
#pragma unroll
        for (int ct = 0; ct < 4; ++ct) acc[rt][ct] = {0.f, 0.f, 0.f, 0.f};

#pragma unroll 1
    for (int kc = 0; kc < NC; kc += 64) {
#pragma unroll
        for (int q = 0; q < 4; ++q) {
            const int row = q * 32 + srow;
            load_lds16(Wb + (size_t)row * NC + kc + ((sslot ^ (row & 7)) << 3),
                       Ws + (q * 32 + (w << 3)) * 64);
        }
#pragma unroll
        for (int r = 0; r < 2; ++r) {
            const int idx = r * 256 + t;
            const int cp = idx >> 4;
            const int p4 = (idx & 15) << 2;
            const float* xp = &x[((size_t)b * NC + kc + 2 * cp) * NN + n0 + p4];
            const float4 v0 = *(const float4*)xp;
            const float4 v1 = *(const float4*)(xp + NN);
            const float* f0 = (const float*)&v0;
            const float* f1 = (const float*)&v1;
#pragma unroll
            for (int j = 0; j < 4; ++j) {
                const int pos = p4 + j;
                const unsigned u = cvt_pk_bf16(f0[j], f1[j]);
                *(unsigned*)&Xs[pos * 64 + ((2 * cp) ^ ((pos & 7) << 3))] = u;
            }
        }
        __syncthreads();
#pragma unroll
        for (int ks = 0; ks < 2; ++ks) {
            s16x8 af[2], bfr[4];
#pragma unroll
            for (int rt = 0; rt < 2; ++rt) {
                const int row = (w << 5) + (rt << 4) + i16;
                af[rt] = *(const s16x8*)&Ws[row * 64 + (((ks << 5) + (g << 3)) ^ ((row & 7) << 3))];
            }
#pragma unroll
            for (int ct = 0; ct < 4; ++ct) {
                const int row = (ct << 4) + i16;
                bfr[ct] = *(const s16x8*)&Xs[row * 64 + (((ks << 5) + (g << 3)) ^ ((row & 7) << 3))];
            }
#pragma unroll
            for (int rt = 0; rt < 2; ++rt)
#pragma unroll
                for (int ct = 0; ct < 4; ++ct)
                    acc[rt][ct] = __builtin_amdgcn_mfma_f32_16x16x32_bf16(af[rt], bfr[ct], acc[rt][ct], 0, 0, 0);
        }
        __syncthreads();
    }

    // ---- epilogue: bias, L2 norm, ksum ----
    const bool isK = (w >= 2);
    const int obase = (w & 1) * 32;
    const float* bias = isK ? bk : bq;
    float bv[2][4];
#pragma unroll
    for (int rt = 0; rt < 2; ++rt)
#pragma unroll
        for (int reg = 0; reg < 4; ++reg)
            bv[rt][reg] = bias[obase + rt * 16 + 4 * g + reg];
#pragma unroll
    for (int rt = 0; rt < 2; ++rt)
#pragma unroll
        for (int ct = 0; ct < 4; ++ct)
#pragma unroll
            for (int reg = 0; reg < 4; ++reg) acc[rt][ct][reg] += bv[rt][reg];

    float sq[4];
#pragma unroll
    for (int ct = 0; ct < 4; ++ct) {
        float s = 0.f;
#pragma unroll
        for (int rt = 0; rt < 2; ++rt)
#pragma unroll
            for (int reg = 0; reg < 4; ++reg) s += acc[rt][ct][reg] * acc[rt][ct][reg];
        s += __shfl_xor(s, 16, 64);
        s += __shfl_xor(s, 32, 64);
        sq[ct] = s;
    }
    ssqL[w][lane] = sq[g];
    __syncthreads();
    const int pairw = (w >> 1) << 1;
    float inv[4];
#pragma unroll
    for (int ct = 0; ct < 4; ++ct) {
        const int p = ct * 16 + i16;
        inv[ct] = rsqrtf(ssqL[pairw][p] + ssqL[pairw + 1][p]);
    }
#pragma unroll
    for (int rt = 0; rt < 2; ++rt)
#pragma unroll
        for (int ct = 0; ct < 4; ++ct)
#pragma unroll
            for (int reg = 0; reg < 4; ++reg) acc[rt][ct][reg] *= inv[ct];

    unsigned short* epQb = WX;         // [pos][64] bf16, swizzled (o ^ ((pos&7)<<3))
    unsigned short* epK  = WX + 8192;  // [o][64]  bf16, slot-swizzled (pos ^ ((o&7)<<3))
    unsigned short* xb   = WX + 4096;  // [c][64]  mat1-phase tile (reuses Ws upper half)
    if (!isK) {
#pragma unroll
        for (int rt = 0; rt < 2; ++rt)
#pragma unroll
            for (int ct = 0; ct < 4; ++ct)
#pragma unroll
                for (int reg = 0; reg < 4; ++reg) {
                    const int o = w * 32 + rt * 16 + 4 * g + reg;
                    const int pos = ct * 16 + i16;
                    epQb[pos * 64 + (o ^ ((pos & 7) << 3))] = f2bf(acc[rt][ct][reg]);
                }
    } else {
#pragma unroll
        for (int rt = 0; rt < 2; ++rt)
#pragma unroll
            for (int reg = 0; reg < 4; ++reg) {
                float s = acc[rt][0][reg] + acc[rt][1][reg] + acc[rt][2][reg] + acc[rt][3][reg];
                s += __shfl_xor(s, 1, 64);
                s += __shfl_xor(s, 2, 64);
                s += __shfl_xor(s, 4, 64);
                s += __shfl_xor(s, 8, 64);
                if (i16 == 0) atomicAdd(&ksum[b * NQ + obase + rt * 16 + 4 * g + reg], s);
            }
#pragma unroll
        for (int rt = 0; rt < 2; ++rt)
#pragma unroll
            for (int ct = 0; ct < 4; ++ct)
#pragma unroll
                for (int reg = 0; reg < 4; ++reg) {
                    const int o = obase + rt * 16 + 4 * g + reg;
                    const int pos = ct * 16 + i16;
                    epK[o * 64 + (pos ^ ((o & 7) << 3))] = f2bf(acc[rt][ct][reg]);
                }
    }
    __syncthreads();
    // Qtb [n][o] (pre-swizzled) linear copy
    {
        const size_t base = ((size_t)b * NN + n0) * 64;
        const uint4* src = (const uint4*)epQb;
#pragma unroll
        for (int r = 0; r < 2; ++r) {
            const int idx = r * 256 + t;
            *(uint4*)&Qtb[base + (size_t)idx * 8] = src[idx];
        }
    }

    // ---- mat1 phase: mat1[b][o][c] += sum_{n in tile} K[o,n]*x[c,n]; xsum += sum_n x ----
#pragma unroll 1
    for (int cc = 0; cc < 8; ++cc) {
        float xpart[2];
#pragma unroll
        for (int r = 0; r < 2; ++r) {
            const int sg = r * 256 + t;
            const int c = sg >> 3, s = sg & 7;
            const float* xp = &x[((size_t)b * NC + cc * 64 + c) * NN + n0 + s * 8];
            const float4 v0 = *(const float4*)xp;
            const float4 v1 = *(const float4*)(xp + 4);
            xpart[r] = (v0.x + v0.y) + (v0.z + v0.w) + (v1.x + v1.y) + (v1.z + v1.w);
            uint4 u;
            u.x = cvt_pk_bf16(v0.x, v0.y);
            u.y = cvt_pk_bf16(v0.z, v0.w);
            u.z = cvt_pk_bf16(v1.x, v1.y);
            u.w = cvt_pk_bf16(v1.z, v1.w);
            *(uint4*)&xb[c * 64 + ((s ^ (c & 7)) << 3)] = u;
        }
#pragma unroll
        for (int r = 0; r < 2; ++r) {
            float sv = xpart[r];
            sv += __shfl_xor(sv, 1, 64);
            sv += __shfl_xor(sv, 2, 64);
            sv += __shfl_xor(sv, 4, 64);
            if ((t & 7) == 0) atomicAdd(&xsum[b * NC + cc * 64 + ((r * 256 + t) >> 3)], sv);
        }
        __syncthreads();
        f32x4 macc[4];
#pragma unroll
        for (int ct = 0; ct < 4; ++ct) macc[ct] = {0.f, 0.f, 0.f, 0.f};
#pragma unroll
        for (int ks = 0; ks < 2; ++ks) {
            const int arow = (w << 4) + i16;
            const s16x8 a8 = *(const s16x8*)&epK[arow * 64 + (((ks << 5) + (g << 3)) ^ ((arow & 7) << 3))];
#pragma unroll
            for (int ct = 0; ct < 4; ++ct) {
                const int crow = (ct << 4) + i16;
                const s16x8 b8 = *(const s16x8*)&xb[crow * 64 + (((ks << 5) + (g << 3)) ^ ((crow & 7) << 3))];
                macc[ct] = __builtin_amdgcn_mfma_f32_16x16x32_bf16(a8, b8, macc[ct], 0, 0, 0);
            }
        }
        const int ob = (w << 4) + 4 * g;
#pragma unroll
        for (int ct = 0; ct < 4; ++ct)
#pragma unroll
            for (int reg = 0; reg < 4; ++reg)
                atomicAdd(&mat1[((size_t)b * NQ + ob + reg) * NC + cc * 64 + (ct << 4) + i16], macc[ct][reg]);
        __syncthreads();
    }
}

// -------- mat2 via bf16 MFMA: m2bT[b][co][o] = sum_c mat1[o][c]*wv[co][c] + ksum0[o]*bv[co]; vsum --------
// grid (8, 8), block 256 (4 waves). Wave w owns o rows [16w, 16w+16).
__launch_bounds__(256, 4)
__global__ void mat2_mfma_kernel(const float* __restrict__ wv, const float* __restrict__ bv,
                                 const unsigned short* __restrict__ Wvb,
                                 const float* __restrict__ mat1, const float* __restrict__ ksum,
                                 const float* __restrict__ xsum,
                                 unsigned short* __restrict__ m2bT, float* __restrict__ vsum) {
    __shared__ __align__(16) unsigned short m1b[64 * 64];  // [o][c] slot-swizzled
    __shared__ __align__(16) unsigned short wvs[64 * 64];  // [co][c] slot-swizzled
    __shared__ float xsl[512];
    const int t = threadIdx.x;
    const int w = t >> 6, lane = t & 63;
    const int g = lane >> 4, i16 = lane & 15;
    const int cot = blockIdx.x, b = blockIdx.y;
    const int co0 = cot * 64;
    const int srow = (w << 3) + (lane >> 3);
    const int sslot = lane & 7;
    xsl[t] = xsum[b * NC + t];
    xsl[256 + t] = xsum[b * NC + 256 + t];

    f32x4 acc[4];
#pragma unroll
    for (int ct = 0; ct < 4; ++ct) acc[ct] = {0.f, 0.f, 0.f, 0.f};

#pragma unroll 1
    for (int cc = 0; cc < NC; cc += 64) {
#pragma unroll
        for (int q = 0; q < 2; ++q) {
            const int row = q * 32 + srow;
            load_lds16(Wvb + (size_t)(co0 + row) * NC + cc + ((sslot ^ (row & 7)) << 3),
                       wvs + (q * 32 + (w << 3)) * 64);
        }
#pragma unroll
        for (int r = 0; r < 2; ++r) {
            const int sg = r * 256 + t;
            const int o = sg >> 3, s = sg & 7;
            const float* mp = &mat1[((size_t)b * NQ + o) * NC + cc + s * 8];
            const float4 v0 = *(const float4*)mp;
            const float4 v1 = *(const float4*)(mp + 4);
            uint4 u;
            u.x = cvt_pk_bf16(v0.x, v0.y);
            u.y = cvt_pk_bf16(v0.z, v0.w);
            u.z = cvt_pk_bf16(v1.x, v1.y);
            u.w = cvt_pk_bf16(v1.z, v1.w);
            *(uint4*)&m1b[o * 64 + ((s ^ (o & 7)) << 3)] = u;
        }
        __syncthreads();
#pragma unroll
        for (int ks = 0; ks < 2; ++ks) {
            const int arow = (w << 4) + i16;
            const s16x8 a8 = *(const s16x8*)&m1b[arow * 64 + (((ks << 5) + (g << 3)) ^ ((arow & 7) << 3))];
#pragma unroll
            for (int ct = 0; ct < 4; ++ct) {
                const int brow = (ct << 4) + i16;
                const s16x8 b8 = *(const s16x8*)&wvs[brow * 64 + (((ks << 5) + (g << 3)) ^ ((brow & 7) << 3))];
                acc[ct] = __builtin_amdgcn_mfma_f32_16x16x32_bf16(a8, b8, acc[ct], 0, 0, 0);
            }
        }
        __syncthreads();
    }
    // vsum: thread covers co_l = t>>2, quarter p = t&3 (128 c each)
    {
        const int co_l = t >> 2, p = t & 3;
        const float* wp = &wv[(size_t)(co0 + co_l) * NC + p * 128];
        float s = 0.f;
#pragma unroll 4
        for (int i = 0; i < 128; ++i) s += wp[i] * xsl[p * 128 + i];
        s += __shfl_xor(s, 1, 64);
        s += __shfl_xor(s, 2, 64);
        if (p == 0) vsum[b * NC + co0 + co_l] = s + (float)NN * bv[co0 + co_l];
    }
    // epilogue: m2bT[co][o] swizzled bf16
    const int ob = (w << 4) + 4 * g;
#pragma unroll
    for (int ct = 0; ct < 4; ++ct)
#pragma unroll
        for (int reg = 0; reg < 4; ++reg) {
            const int o = ob + reg;
            const int co = co0 + (ct << 4) + i16;
            m2bT[((size_t)b * NC + co) * NQ + (o ^ ((co & 7) << 3))] =
                f2bf(acc[ct][reg] + ksum[b * NQ + o] * bv[co]);
        }
}

// -------- out = x + gamma * (vsum[c] + Qt^T mat2) * tailor, via bf16 MFMA --------  (unchanged)
__launch_bounds__(256, 4)
__global__ void final_mfma_kernel(const float* __restrict__ x, const unsigned short* __restrict__ Qtb,
                                  const float* __restrict__ ksum, const unsigned short* __restrict__ m2bT,
                                  const float* __restrict__ vsum, const float* __restrict__ gamma,
                                  float* __restrict__ out) {
    __shared__ __align__(16) unsigned short Qs[64 * 64];
    __shared__ __align__(16) unsigned short Ms[2][64 * 64];
    __shared__ float vsall[512];
    __shared__ float ksl[64];
    __shared__ float tl[64];
    const int t = threadIdx.x;
    const int w = t >> 6, lane = t & 63;
    const int g = lane >> 4, i16 = lane & 15;
    const int b = blockIdx.y;
    const int n0 = blockIdx.x * 64;

    const unsigned short* qg = Qtb + ((size_t)b * NN + n0) * 64;
    const unsigned short* mg = m2bT + (size_t)b * NC * 64;
#pragma unroll
    for (int r = 0; r < 2; ++r) {
        const int off = (w * 2 + r) * 512;
        load_lds16(qg + off + lane * 8, Qs + off);
        load_lds16(mg + off + lane * 8, &Ms[0][off]);
    }
    vsall[t] = vsum[b * NC + t];
    vsall[256 + t] = vsum[b * NC + 256 + t];
    if (t < 64) ksl[t] = ksum[b * NQ + t] + FEPS;
    __syncthreads();
    if (t < 64) {
        float s = 0.f;
        const int sw = (t & 7) << 3;
#pragma unroll 8
        for (int o = 0; o < 64; ++o) {
            union { unsigned u; float f; } cv;
            cv.u = (unsigned)Qs[t * 64 + o] << 16;
            s += cv.f * ksl[o ^ sw];
        }
        tl[t] = 1.0f / ((float)NN + s);
    }
    s16x8 af[4][2];
#pragma unroll
    for (int mt = 0; mt < 4; ++mt)
#pragma unroll
        for (int ks = 0; ks < 2; ++ks) {
            const int row = mt * 16 + i16;
            af[mt][ks] = *(const s16x8*)&Qs[row * 64 + (((ks << 5) + (g << 3)) ^ ((row & 7) << 3))];
        }
    const float gm = gamma[0];
    const int c_local = w * 16 + i16;
    __syncthreads();

#pragma unroll 1
    for (int cc8 = 0; cc8 < 8; ++cc8) {
        if (cc8 < 7) {
#pragma unroll
            for (int r = 0; r < 2; ++r) {
                const int off = (w * 2 + r) * 512;
                load_lds16(mg + (cc8 + 1) * 4096 + off + lane * 8, &Ms[(cc8 + 1) & 1][off]);
            }
        }
        const unsigned short* mbuf = Ms[cc8 & 1];
        s16x8 b8[2];
#pragma unroll
        for (int ks = 0; ks < 2; ++ks)
            b8[ks] = *(const s16x8*)&mbuf[c_local * 64 + (((ks << 5) + (g << 3)) ^ ((i16 & 7) << 3))];
        f32x4 acc[4];
#pragma unroll
        for (int mt = 0; mt < 4; ++mt) acc[mt] = {0.f, 0.f, 0.f, 0.f};
#pragma unroll
        for (int ks = 0; ks < 2; ++ks)
#pragma unroll
            for (int mt = 0; mt < 4; ++mt)
                acc[mt] = __builtin_amdgcn_mfma_f32_16x16x32_bf16(af[mt][ks], b8[ks], acc[mt], 0, 0, 0);
        const int c = cc8 * 64 + c_local;
        const float vsv = vsall[c];
        const size_t rowbase = ((size_t)b * NC + c) * NN + n0;
#pragma unroll
        for (int mt = 0; mt < 4; ++mt) {
            const int p = mt * 16 + 4 * g;
            const float4 xv = *(const float4*)&x[rowbase + p];
            const float4 t4 = *(const float4*)&tl[p];
            float4 ov;
            ov.x = xv.x + gm * (vsv + acc[mt][0]) * t4.x;
            ov.y = xv.y + gm * (vsv + acc[mt][1]) * t4.y;
            ov.z = xv.z + gm * (vsv + acc[mt][2]) * t4.z;
            ov.w = xv.w + gm * (vsv + acc[mt][3]) * t4.w;
            *(float4*)&out[rowbase + p] = ov;
        }
        __syncthreads();
    }
}

extern "C" void kernel_launch(void* const* d_in, const int* in_sizes, int n_in,
                              void* d_out, int out_size, void* d_ws, size_t ws_size,
                              hipStream_t stream) {
    (void)in_sizes; (void)n_in; (void)out_size; (void)ws_size;
    const float* x     = (const float*)d_in[0];
    const float* wq    = (const float*)d_in[1];
    const float* bq    = (const float*)d_in[2];
    const float* wk    = (const float*)d_in[3];
    const float* bk    = (const float*)d_in[4];
    const float* wv    = (const float*)d_in[5];
    const float* bv    = (const float*)d_in[6];
    const float* gamma = (const float*)d_in[7];
    float* out = (float*)d_out;
    float* ws  = (float*)d_ws;

    unsigned short* Qtb  = (unsigned short*)(ws + OFF_Q);
    unsigned short* Wvb  = (unsigned short*)(ws + OFF_KT);
    float* ksum          = ws + OFF_KSUM;
    float* xsum          = ws + OFF_XSUM;
    float* m1            = ws + OFF_M1;
    unsigned short* m2b  = (unsigned short*)(ws + OFF_M2);
    float* vsum          = ws + OFF_VSUM;
    unsigned short* Wb   = (unsigned short*)(ws + OFF_WB);

    // zero all atomically-accumulated buffers (ksum, xsum, mat1 are contiguous)
    hipMemsetAsync(ksum, 0, (size_t)(NB * NQ + NB * NC + NB * NQ * NC) * sizeof(float), stream);

    prep_w_kernel<<<dim3(80), 256, 0, stream>>>(wq, wk, wv, Wb, Wvb);
    qk_mfma_kernel<<<dim3(NN / 64, NB), 256, 0, stream>>>(x, Wb, bq, bk, Qtb, ksum, xsum, m1);
    mat2_mfma_kernel<<<dim3(8, NB), 256, 0, stream>>>(wv, bv, Wvb, m1, ksum, xsum, m2b, vsum);
    final_mfma_kernel<<<dim3(NN / 64, NB), 256, 0, stream>>>(x, Qtb, ksum, m2b, vsum, gamma, out);
}